// Round 20
// baseline (37.481 us; speedup 1.0000x reference)
//
#include <hip/hip_runtime.h>
#include <hip/hip_bf16.h>

#define N_TOT 8192
#define B_HALF 4096
#define D_DIM 256
#define NQUAD 496            // sum floor((64-ti)/4): 4-tile units
#define NSING 96             // sum (64-ti)%4: 1-tile tail units
#define NBLK (NQUAD + NSING) // 592, one dispatch, all co-resident at 3/CU

typedef __attribute__((ext_vector_type(4))) float f32x4;
typedef unsigned long long u64;

// S8SCALE = sqrt(256 * 2*log2(e)). zq = fp8(S8SCALE * z/|z|), so the MFMA acc
// = S8SCALE^2 * sim = 256 * sim * 2*log2(e)  ->  exp(sim/T) = exp2(acc/256).
#define S8SCALE 27.178307f
#define LN2 0.69314718056f

// ---- normalize -> fp8, TRANSPOSED store zt[g][row] (g = 8B K-chunk 0..31) --
// 512 blocks x 8 pairs. LDS transpose: full-16B coalesced chunk-major writes.
__global__ __launch_bounds__(256) void k_norm(const float* __restrict__ p1,
                                              const float* __restrict__ p2,
                                              u64* __restrict__ zt,
                                              float* __restrict__ self,
                                              float* __restrict__ partials,
                                              float* __restrict__ rowsum,
                                              float* __restrict__ out) {
  __shared__ unsigned sm[2][8][64]; // [half][row-in-block][4B word]
  __shared__ float red[4];
  int tid = threadIdx.x;
  int lane = tid & 63;
  int w = tid >> 6;                 // wave 0..3
  int bid = blockIdx.x;
  int i0 = bid * 8;
  if (tid < 16) rowsum[bid * 16 + tid] = 0.0f;
  if (bid == 0 && tid == 0) out[0] = 0.0f;

  float possum = 0.f;
#pragma unroll
  for (int k = 0; k < 2; ++k) {
    int r = w * 2 + k;              // row-in-block 0..7
    int i = i0 + r;                 // pair index 0..4095
    float4 a = *reinterpret_cast<const float4*>(p1 + (size_t)i * D_DIM + lane * 4);
    float4 b = *reinterpret_cast<const float4*>(p2 + (size_t)i * D_DIM + lane * 4);
    float ssa = a.x * a.x + a.y * a.y + a.z * a.z + a.w * a.w;
    float ssb = b.x * b.x + b.y * b.y + b.z * b.z + b.w * b.w;
    float d = a.x * b.x + a.y * b.y + a.z * b.z + a.w * b.w;
#pragma unroll
    for (int m = 1; m < 64; m <<= 1) {
      ssa += __shfl_xor(ssa, m, 64);
      ssb += __shfl_xor(ssb, m, 64);
      d += __shfl_xor(d, m, 64);
    }
    float na = fmaxf(sqrtf(ssa), 1e-8f);
    float nb = fmaxf(sqrtf(ssb), 1e-8f);
    float ia = S8SCALE / na, ib = S8SCALE / nb;

    int wa = __builtin_amdgcn_cvt_pk_fp8_f32(a.x * ia, a.y * ia, 0, false);
    wa = __builtin_amdgcn_cvt_pk_fp8_f32(a.z * ia, a.w * ia, wa, true);
    int wb = __builtin_amdgcn_cvt_pk_fp8_f32(b.x * ib, b.y * ib, 0, false);
    wb = __builtin_amdgcn_cvt_pk_fp8_f32(b.z * ib, b.w * ib, wb, true);
    sm[0][r][lane] = (unsigned)wa;
    sm[1][r][lane] = (unsigned)wb;

    float va0 = __builtin_amdgcn_cvt_f32_fp8(wa, 0);
    float va1 = __builtin_amdgcn_cvt_f32_fp8(wa, 1);
    float va2 = __builtin_amdgcn_cvt_f32_fp8(wa, 2);
    float va3 = __builtin_amdgcn_cvt_f32_fp8(wa, 3);
    float vb0 = __builtin_amdgcn_cvt_f32_fp8(wb, 0);
    float vb1 = __builtin_amdgcn_cvt_f32_fp8(wb, 1);
    float vb2 = __builtin_amdgcn_cvt_f32_fp8(wb, 2);
    float vb3 = __builtin_amdgcn_cvt_f32_fp8(wb, 3);
    float sqa = va0 * va0 + va1 * va1 + va2 * va2 + va3 * va3;
    float sqb = vb0 * vb0 + vb1 * vb1 + vb2 * vb2 + vb3 * vb3;
#pragma unroll
    for (int m = 1; m < 64; m <<= 1) {
      sqa += __shfl_xor(sqa, m, 64);
      sqb += __shfl_xor(sqb, m, 64);
    }
    if (lane == 0) {
      self[i] = sqa * (1.0f / 256.0f);       // exponent domain (acc/256)
      self[i + B_HALF] = sqb * (1.0f / 256.0f);
      possum += -4.0f * d / (na * nb) * (1.0f / (float)N_TOT);
    }
  }
  if (lane == 0) red[w] = possum;
  __syncthreads();
  if (tid == 0) partials[bid] = red[0] + red[1] + red[2] + red[3];

  // transposed write-out: thread t -> half h, chunk g (0..31), row-quarter qr
  {
    int h = tid >> 7;               // 0..1
    int rem = tid & 127;
    int g = rem >> 2;               // 0..31
    int qr = rem & 3;               // rows qr*2, qr*2+1
    uint4 v;
    v.x = sm[h][qr * 2][g * 2];
    v.y = sm[h][qr * 2][g * 2 + 1];
    v.z = sm[h][qr * 2 + 1][g * 2];
    v.w = sm[h][qr * 2 + 1][g * 2 + 1];
    size_t idx8 = (size_t)g * N_TOT + h * B_HALF + i0 + qr * 2; // 8B units
    *reinterpret_cast<uint4*>((char*)zt + idx8 * 8) = v;
  }
}

// ---- symmetric fused fp8 GEMM + exp sums; NO LDS, coalesced chunk-major ----
// ONE dispatch, 592 blocks, ALL co-resident at 3 blocks/CU (768 slots):
// single-buffered bf keeps VGPR ~160 under the (256,3) cap of 170; load
// latency is covered by 3-way cross-wave overlap instead of double-buffering.
__global__ __launch_bounds__(256, 3) void k_sim(const u64* __restrict__ zt,
                                                float* __restrict__ rowsum) {
  const int bid = blockIdx.x;
  int ti = 0, cum = 0, tj0, nt;
  if (bid < NQUAD) {
    while (cum + ((64 - ti) >> 2) <= bid) { cum += (64 - ti) >> 2; ++ti; }
    tj0 = ti + 4 * (bid - cum);
    nt = 4;
  } else {
    const int s = bid - NQUAD;
    while (cum + ((64 - ti) & 3) <= s) { cum += (64 - ti) & 3; ++ti; }
    tj0 = 64 - ((64 - ti) & 3) + (s - cum);
    nt = 1;
  }
  const int nht = 2 * nt;   // 64-col steps
  const bool diag = (tj0 == ti);
  const int rowbase = ti * 128;
  const int colchunk = tj0 * 128;

  const int tid = threadIdx.x;
  const int lane = tid & 63;
  const int wid = tid >> 6;
  const int wm = wid >> 1;  // row half
  const int wn = wid & 1;   // col half
  const int hi = lane >> 4; // 0..3
  const int lo = lane & 15;

  // per-lane bases in 8B units; chunk for (k8 g', hi) = g'*4+hi -> stride 4*8192
  const size_t baseA = (size_t)hi * N_TOT + rowbase + wm * 64 + lo;
  const size_t baseB = (size_t)hi * N_TOT + colchunk + wn * 32 + lo;

  // ---- A fragments (64 VGPR), one-time coalesced loads ----
  long af[4][8];
#pragma unroll
  for (int m = 0; m < 4; ++m)
#pragma unroll
    for (int g = 0; g < 8; ++g)
      af[m][g] = (long)zt[(size_t)g * 4 * N_TOT + baseA + m * 16];

  float pr[4][4] = {}; // [m][r] per-row exp partials (rows of ti)

  // single bf buffer (32 VGPR); loads issue at loop top, waitcnt before MFMA
  long bf[2][8];
#pragma unroll 1
  for (int t = 0; t < nht; ++t) {
#pragma unroll
    for (int n = 0; n < 2; ++n)
#pragma unroll
      for (int g = 0; g < 8; ++g)
        bf[n][g] = (long)zt[(size_t)g * 4 * N_TOT + baseB + t * 64 + n * 16];

    f32x4 acc[4][2];
#pragma unroll
    for (int m = 0; m < 4; ++m)
#pragma unroll
      for (int n = 0; n < 2; ++n) acc[m][n] = (f32x4){0.f, 0.f, 0.f, 0.f};
#pragma unroll
    for (int g = 0; g < 8; ++g)
#pragma unroll
      for (int m = 0; m < 4; ++m) {
        acc[m][0] = __builtin_amdgcn_mfma_f32_16x16x32_fp8_fp8(
            af[m][g], bf[0][g], acc[m][0], 0, 0, 0);
        acc[m][1] = __builtin_amdgcn_mfma_f32_16x16x32_fp8_fp8(
            af[m][g], bf[1][g], acc[m][1], 0, 0, 0);
      }

    // retire: exponent = acc/256; row partials + this step's col partials
    float pc[2] = {0.f, 0.f};
#pragma unroll
    for (int m = 0; m < 4; ++m)
#pragma unroll
      for (int n = 0; n < 2; ++n) {
        float e0 = __builtin_amdgcn_exp2f(acc[m][n][0] * (1.0f / 256.0f));
        float e1 = __builtin_amdgcn_exp2f(acc[m][n][1] * (1.0f / 256.0f));
        float e2 = __builtin_amdgcn_exp2f(acc[m][n][2] * (1.0f / 256.0f));
        float e3 = __builtin_amdgcn_exp2f(acc[m][n][3] * (1.0f / 256.0f));
        pr[m][0] += e0; pr[m][1] += e1; pr[m][2] += e2; pr[m][3] += e3;
        pc[n] += (e0 + e1) + (e2 + e3);
      }

    // col sums -> rows of tj (skip the diagonal tile: first 2 steps when diag)
    if (!(diag && t < 2)) {
#pragma unroll
      for (int n = 0; n < 2; ++n) {
        float v = pc[n];
        v += __shfl_xor(v, 16, 64);
        v += __shfl_xor(v, 32, 64);
        if (hi == 0)
          atomicAdd(&rowsum[colchunk + t * 64 + wn * 32 + n * 16 + lo], v);
      }
    }
  }

  // row sums -> rows of ti (reduce over the 16 col-lanes)
#pragma unroll
  for (int m = 0; m < 4; ++m)
#pragma unroll
    for (int r = 0; r < 4; ++r) {
      float s = pr[m][r];
      s += __shfl_xor(s, 1, 64);
      s += __shfl_xor(s, 2, 64);
      s += __shfl_xor(s, 4, 64);
      s += __shfl_xor(s, 8, 64);
      if (lo == 0)
        atomicAdd(&rowsum[rowbase + wm * 64 + m * 16 + hi * 4 + r], s);
    }
}

// ---- final: 32 blocks, out += sum(log(rowsum-exp2(self)))/n + partials -----
__global__ __launch_bounds__(256) void k_lse(const float* __restrict__ rowsum,
                                             const float* __restrict__ self,
                                             const float* __restrict__ partials,
                                             float* __restrict__ out) {
  int tid = threadIdx.x;
  int i = blockIdx.x * 256 + tid;
  float rs = rowsum[i] - __builtin_amdgcn_exp2f(self[i]);
  float v = __builtin_amdgcn_logf(rs) * (LN2 / (float)N_TOT); // v_log_f32 = log2
  if (tid < 16) v += partials[blockIdx.x * 16 + tid]; // 512 partials / 32 blocks
#pragma unroll
  for (int m = 1; m < 64; m <<= 1) v += __shfl_xor(v, m, 64);
  __shared__ float red[4];
  if ((tid & 63) == 0) red[tid >> 6] = v;
  __syncthreads();
  if (tid == 0) atomicAdd(out, red[0] + red[1] + red[2] + red[3]);
}

extern "C" void kernel_launch(void* const* d_in, const int* in_sizes, int n_in,
                              void* d_out, int out_size, void* d_ws, size_t ws_size,
                              hipStream_t stream) {
  const float* p1 = (const float*)d_in[0];
  const float* p2 = (const float*)d_in[1];
  float* out = (float*)d_out;
  char* ws = (char*)d_ws;

  u64* zt = (u64*)ws;                                            // 2 MB fp8 (transposed)
  float* self = (float*)(ws + 2097152);                          // 32 KB
  float* rowsum = self + N_TOT;                                  // 32 KB
  float* partials = rowsum + N_TOT;                              // 2 KB

  k_norm<<<N_TOT / 16, 256, 0, stream>>>(p1, p2, zt, self, partials, rowsum, out);
  k_sim<<<NBLK, 256, 0, stream>>>(zt, rowsum);
  k_lse<<<N_TOT / 256, 256, 0, stream>>>(rowsum, self, partials, out);
}

// Round 21
// 36.087 us; speedup vs baseline: 1.0386x; 1.0386x over previous
//
#include <hip/hip_runtime.h>
#include <hip/hip_bf16.h>

#define N_TOT 8192
#define B_HALF 4096
#define D_DIM 256
#define NQUAD 496            // sum floor((64-ti)/4): 4-tile units
#define NSING 96             // sum (64-ti)%4: 1-tile tail units
#define NBLK (NQUAD + NSING) // 592, one dispatch
#define NREP 8               // rowsum replicas (atomic-contention spread)

typedef __attribute__((ext_vector_type(4))) float f32x4;
typedef unsigned long long u64;

// S8SCALE = sqrt(256 * 2*log2(e)). zq = fp8(S8SCALE * z/|z|), so the MFMA acc
// = S8SCALE^2 * sim = 256 * sim * 2*log2(e)  ->  exp(sim/T) = exp2(acc/256).
#define S8SCALE 27.178307f
#define LN2 0.69314718056f

// ---- normalize -> fp8, TRANSPOSED store zt[g][row] (g = 8B K-chunk 0..31) --
__global__ __launch_bounds__(256) void k_norm(const float* __restrict__ p1,
                                              const float* __restrict__ p2,
                                              u64* __restrict__ zt,
                                              float* __restrict__ self,
                                              float* __restrict__ partials,
                                              float* __restrict__ RS,
                                              float* __restrict__ out) {
  __shared__ unsigned sm[2][8][64]; // [half][row-in-block][4B word]
  __shared__ float red[4];
  int tid = threadIdx.x;
  int lane = tid & 63;
  int w = tid >> 6;                 // wave 0..3
  int bid = blockIdx.x;
  int i0 = bid * 8;
  // zero RS: 8 replicas x 8192 floats = 256KB; 512 blocks x 32 x 16B
  if (tid < 32) reinterpret_cast<f32x4*>(RS)[bid * 32 + tid] = (f32x4){0.f, 0.f, 0.f, 0.f};
  if (bid == 0 && tid == 0) out[0] = 0.0f;

  float possum = 0.f;
#pragma unroll
  for (int k = 0; k < 2; ++k) {
    int r = w * 2 + k;              // row-in-block 0..7
    int i = i0 + r;                 // pair index 0..4095
    float4 a = *reinterpret_cast<const float4*>(p1 + (size_t)i * D_DIM + lane * 4);
    float4 b = *reinterpret_cast<const float4*>(p2 + (size_t)i * D_DIM + lane * 4);
    float ssa = a.x * a.x + a.y * a.y + a.z * a.z + a.w * a.w;
    float ssb = b.x * b.x + b.y * b.y + b.z * b.z + b.w * b.w;
    float d = a.x * b.x + a.y * b.y + a.z * b.z + a.w * b.w;
#pragma unroll
    for (int m = 1; m < 64; m <<= 1) {
      ssa += __shfl_xor(ssa, m, 64);
      ssb += __shfl_xor(ssb, m, 64);
      d += __shfl_xor(d, m, 64);
    }
    float na = fmaxf(sqrtf(ssa), 1e-8f);
    float nb = fmaxf(sqrtf(ssb), 1e-8f);
    float ia = S8SCALE / na, ib = S8SCALE / nb;

    int wa = __builtin_amdgcn_cvt_pk_fp8_f32(a.x * ia, a.y * ia, 0, false);
    wa = __builtin_amdgcn_cvt_pk_fp8_f32(a.z * ia, a.w * ia, wa, true);
    int wb = __builtin_amdgcn_cvt_pk_fp8_f32(b.x * ib, b.y * ib, 0, false);
    wb = __builtin_amdgcn_cvt_pk_fp8_f32(b.z * ib, b.w * ib, wb, true);
    sm[0][r][lane] = (unsigned)wa;
    sm[1][r][lane] = (unsigned)wb;

    float va0 = __builtin_amdgcn_cvt_f32_fp8(wa, 0);
    float va1 = __builtin_amdgcn_cvt_f32_fp8(wa, 1);
    float va2 = __builtin_amdgcn_cvt_f32_fp8(wa, 2);
    float va3 = __builtin_amdgcn_cvt_f32_fp8(wa, 3);
    float vb0 = __builtin_amdgcn_cvt_f32_fp8(wb, 0);
    float vb1 = __builtin_amdgcn_cvt_f32_fp8(wb, 1);
    float vb2 = __builtin_amdgcn_cvt_f32_fp8(wb, 2);
    float vb3 = __builtin_amdgcn_cvt_f32_fp8(wb, 3);
    float sqa = va0 * va0 + va1 * va1 + va2 * va2 + va3 * va3;
    float sqb = vb0 * vb0 + vb1 * vb1 + vb2 * vb2 + vb3 * vb3;
#pragma unroll
    for (int m = 1; m < 64; m <<= 1) {
      sqa += __shfl_xor(sqa, m, 64);
      sqb += __shfl_xor(sqb, m, 64);
    }
    if (lane == 0) {
      self[i] = sqa * (1.0f / 256.0f);       // exponent domain (acc/256)
      self[i + B_HALF] = sqb * (1.0f / 256.0f);
      possum += -4.0f * d / (na * nb) * (1.0f / (float)N_TOT);
    }
  }
  if (lane == 0) red[w] = possum;
  __syncthreads();
  if (tid == 0) partials[bid] = red[0] + red[1] + red[2] + red[3];

  // transposed write-out: thread t -> half h, chunk g (0..31), row-quarter qr
  {
    int h = tid >> 7;               // 0..1
    int rem = tid & 127;
    int g = rem >> 2;               // 0..31
    int qr = rem & 3;               // rows qr*2, qr*2+1
    uint4 v;
    v.x = sm[h][qr * 2][g * 2];
    v.y = sm[h][qr * 2][g * 2 + 1];
    v.z = sm[h][qr * 2 + 1][g * 2];
    v.w = sm[h][qr * 2 + 1][g * 2 + 1];
    size_t idx8 = (size_t)g * N_TOT + h * B_HALF + i0 + qr * 2; // 8B units
    *reinterpret_cast<uint4*>((char*)zt + idx8 * 8) = v;
  }
}

// ---- symmetric fused fp8 GEMM + exp sums; NO LDS, coalesced chunk-major ----
// Atomics spread over 8 replicated accumulators (replica = bid&7) to divide
// per-cache-line RMW contention by 8. Otherwise identical to R20.
__global__ __launch_bounds__(256, 3) void k_sim(const u64* __restrict__ zt,
                                                float* __restrict__ RS) {
  const int bid = blockIdx.x;
  int ti = 0, cum = 0, tj0, nt;
  if (bid < NQUAD) {
    while (cum + ((64 - ti) >> 2) <= bid) { cum += (64 - ti) >> 2; ++ti; }
    tj0 = ti + 4 * (bid - cum);
    nt = 4;
  } else {
    const int s = bid - NQUAD;
    while (cum + ((64 - ti) & 3) <= s) { cum += (64 - ti) & 3; ++ti; }
    tj0 = 64 - ((64 - ti) & 3) + (s - cum);
    nt = 1;
  }
  const int nht = 2 * nt;   // 64-col steps
  const bool diag = (tj0 == ti);
  const int rowbase = ti * 128;
  const int colchunk = tj0 * 128;
  float* __restrict__ rowsum = RS + (size_t)(bid & (NREP - 1)) * N_TOT;

  const int tid = threadIdx.x;
  const int lane = tid & 63;
  const int wid = tid >> 6;
  const int wm = wid >> 1;  // row half
  const int wn = wid & 1;   // col half
  const int hi = lane >> 4; // 0..3
  const int lo = lane & 15;

  // per-lane bases in 8B units; chunk for (k8 g', hi) = g'*4+hi -> stride 4*8192
  const size_t baseA = (size_t)hi * N_TOT + rowbase + wm * 64 + lo;
  const size_t baseB = (size_t)hi * N_TOT + colchunk + wn * 32 + lo;

  // ---- A fragments (64 VGPR), one-time coalesced loads ----
  long af[4][8];
#pragma unroll
  for (int m = 0; m < 4; ++m)
#pragma unroll
    for (int g = 0; g < 8; ++g)
      af[m][g] = (long)zt[(size_t)g * 4 * N_TOT + baseA + m * 16];

  float pr[4][4] = {}; // [m][r] per-row exp partials (rows of ti)

  // single bf buffer (32 VGPR); loads issue at loop top, waitcnt before MFMA
  long bf[2][8];
#pragma unroll 1
  for (int t = 0; t < nht; ++t) {
#pragma unroll
    for (int n = 0; n < 2; ++n)
#pragma unroll
      for (int g = 0; g < 8; ++g)
        bf[n][g] = (long)zt[(size_t)g * 4 * N_TOT + baseB + t * 64 + n * 16];

    f32x4 acc[4][2];
#pragma unroll
    for (int m = 0; m < 4; ++m)
#pragma unroll
      for (int n = 0; n < 2; ++n) acc[m][n] = (f32x4){0.f, 0.f, 0.f, 0.f};
#pragma unroll
    for (int g = 0; g < 8; ++g)
#pragma unroll
      for (int m = 0; m < 4; ++m) {
        acc[m][0] = __builtin_amdgcn_mfma_f32_16x16x32_fp8_fp8(
            af[m][g], bf[0][g], acc[m][0], 0, 0, 0);
        acc[m][1] = __builtin_amdgcn_mfma_f32_16x16x32_fp8_fp8(
            af[m][g], bf[1][g], acc[m][1], 0, 0, 0);
      }

    // retire: exponent = acc/256; row partials + this step's col partials
    float pc[2] = {0.f, 0.f};
#pragma unroll
    for (int m = 0; m < 4; ++m)
#pragma unroll
      for (int n = 0; n < 2; ++n) {
        float e0 = __builtin_amdgcn_exp2f(acc[m][n][0] * (1.0f / 256.0f));
        float e1 = __builtin_amdgcn_exp2f(acc[m][n][1] * (1.0f / 256.0f));
        float e2 = __builtin_amdgcn_exp2f(acc[m][n][2] * (1.0f / 256.0f));
        float e3 = __builtin_amdgcn_exp2f(acc[m][n][3] * (1.0f / 256.0f));
        pr[m][0] += e0; pr[m][1] += e1; pr[m][2] += e2; pr[m][3] += e3;
        pc[n] += (e0 + e1) + (e2 + e3);
      }

    // col sums -> rows of tj (skip the diagonal tile: first 2 steps when diag)
    if (!(diag && t < 2)) {
#pragma unroll
      for (int n = 0; n < 2; ++n) {
        float v = pc[n];
        v += __shfl_xor(v, 16, 64);
        v += __shfl_xor(v, 32, 64);
        if (hi == 0)
          atomicAdd(&rowsum[colchunk + t * 64 + wn * 32 + n * 16 + lo], v);
      }
    }
  }

  // row sums -> rows of ti (reduce over the 16 col-lanes)
#pragma unroll
  for (int m = 0; m < 4; ++m)
#pragma unroll
    for (int r = 0; r < 4; ++r) {
      float s = pr[m][r];
      s += __shfl_xor(s, 1, 64);
      s += __shfl_xor(s, 2, 64);
      s += __shfl_xor(s, 4, 64);
      s += __shfl_xor(s, 8, 64);
      if (lo == 0)
        atomicAdd(&rowsum[rowbase + wm * 64 + m * 16 + hi * 4 + r], s);
    }
}

// ---- final: 32 blocks, out += sum(log(sum_r RS[r] - exp2(self)))/n ---------
__global__ __launch_bounds__(256) void k_lse(const float* __restrict__ RS,
                                             const float* __restrict__ self,
                                             const float* __restrict__ partials,
                                             float* __restrict__ out) {
  int tid = threadIdx.x;
  int i = blockIdx.x * 256 + tid;
  float rs = 0.f;
#pragma unroll
  for (int r = 0; r < NREP; ++r) rs += RS[(size_t)r * N_TOT + i];
  rs -= __builtin_amdgcn_exp2f(self[i]);
  float v = __builtin_amdgcn_logf(rs) * (LN2 / (float)N_TOT); // v_log_f32 = log2
  if (tid < 16) v += partials[blockIdx.x * 16 + tid]; // 512 partials / 32 blocks
#pragma unroll
  for (int m = 1; m < 64; m <<= 1) v += __shfl_xor(v, m, 64);
  __shared__ float red[4];
  if ((tid & 63) == 0) red[tid >> 6] = v;
  __syncthreads();
  if (tid == 0) atomicAdd(out, red[0] + red[1] + red[2] + red[3]);
}

extern "C" void kernel_launch(void* const* d_in, const int* in_sizes, int n_in,
                              void* d_out, int out_size, void* d_ws, size_t ws_size,
                              hipStream_t stream) {
  const float* p1 = (const float*)d_in[0];
  const float* p2 = (const float*)d_in[1];
  float* out = (float*)d_out;
  char* ws = (char*)d_ws;

  u64* zt = (u64*)ws;                                            // 2 MB fp8 (transposed)
  float* self = (float*)(ws + 2097152);                          // 32 KB
  float* RS = self + N_TOT;                                      // 256 KB (8 replicas)
  float* partials = RS + (size_t)NREP * N_TOT;                   // 2 KB

  k_norm<<<N_TOT / 16, 256, 0, stream>>>(p1, p2, zt, self, partials, RS, out);
  k_sim<<<NBLK, 256, 0, stream>>>(zt, RS);
  k_lse<<<N_TOT / 256, 256, 0, stream>>>(RS, self, partials, out);
}